// Round 1
// baseline (32.548 us; speedup 1.0000x reference)
//
#include <hip/hip_runtime.h>

#define KER    15
#define PAD    7
#define IMG_H  512
#define IMG_W  512
#define TILE_W 64
#define TILE_H 32
#define SW     (TILE_W + 2 * PAD)   // 78
#define SH     (TILE_H + 2 * PAD)   // 46
#define SW_PAD 80                   // pad LDS row to avoid pathological strides

__global__ __launch_bounds__(256)
void dark_channel_kernel(const float* __restrict__ x, float* __restrict__ out) {
    __shared__ float smin[SH][SW_PAD];   // channel-min halo tile
    __shared__ float hmin[SH][TILE_W];   // after horizontal 15-min

    const int tid = threadIdx.x;
    const int bx  = blockIdx.x;   // tile col  (0..7)
    const int by  = blockIdx.y;   // tile row  (0..15)
    const int b   = blockIdx.z;   // batch     (0..15)

    const long base = (long)b * 3 * IMG_H * IMG_W;
    const int  row0 = by * TILE_H - PAD;
    const int  col0 = bx * TILE_W - PAD;

    // ---- stage 1: load halo region, reflect-pad, min over 3 channels ----
    for (int idx = tid; idx < SH * SW; idx += 256) {
        int r = idx / SW;
        int c = idx - r * SW;
        int gr = row0 + r;
        gr = gr < 0 ? -gr : (gr > IMG_H - 1 ? 2 * (IMG_H - 1) - gr : gr);
        int gc = col0 + c;
        gc = gc < 0 ? -gc : (gc > IMG_W - 1 ? 2 * (IMG_W - 1) - gc : gc);
        long off = base + (long)gr * IMG_W + gc;
        float v0 = x[off];
        float v1 = x[off + IMG_H * IMG_W];
        float v2 = x[off + 2 * IMG_H * IMG_W];
        smin[r][c] = fminf(fminf(v0, v1), v2);
    }
    __syncthreads();

    // ---- stage 2: horizontal 15-wide min ----
    for (int idx = tid; idx < SH * TILE_W; idx += 256) {
        int r = idx >> 6;          // /64
        int c = idx & 63;
        float m = smin[r][c];
        #pragma unroll
        for (int k = 1; k < KER; ++k) m = fminf(m, smin[r][c + k]);
        hmin[r][c] = m;
    }
    __syncthreads();

    // ---- stage 3: vertical 15-tall min + coalesced store ----
    for (int idx = tid; idx < TILE_H * TILE_W; idx += 256) {
        int r = idx >> 6;
        int c = idx & 63;
        float m = hmin[r][c];
        #pragma unroll
        for (int k = 1; k < KER; ++k) m = fminf(m, hmin[r + k][c]);
        out[(long)b * IMG_H * IMG_W + (long)(by * TILE_H + r) * IMG_W + bx * TILE_W + c] = m;
    }
}

extern "C" void kernel_launch(void* const* d_in, const int* in_sizes, int n_in,
                              void* d_out, int out_size, void* d_ws, size_t ws_size,
                              hipStream_t stream) {
    const float* x = (const float*)d_in[0];
    float* out = (float*)d_out;
    dim3 grid(IMG_W / TILE_W, IMG_H / TILE_H, 16);  // 8 x 16 x 16 = 2048 blocks
    dim3 block(256);
    dark_channel_kernel<<<grid, block, 0, stream>>>(x, out);
}

// Round 2
// 28.613 us; speedup vs baseline: 1.1375x; 1.1375x over previous
//
#include <hip/hip_runtime.h>

#define KER    15
#define PAD    7
#define IMG    512
#define TILE_W 64
#define TILE_H 32
#define SH     (TILE_H + 2 * PAD)   // 46
#define SW2    80                   // aligned halo width (need 78, load 80)
#define CH_STRIDE (IMG * IMG)       // 262144

__device__ __forceinline__ int reflect_idx(int i) {
    i = i < 0 ? -i : i;
    return i > IMG - 1 ? 2 * (IMG - 1) - i : i;
}

__device__ __forceinline__ float4 fmin4(float4 a, float4 b) {
    float4 r;
    r.x = fminf(a.x, b.x); r.y = fminf(a.y, b.y);
    r.z = fminf(a.z, b.z); r.w = fminf(a.w, b.w);
    return r;
}

__global__ __launch_bounds__(256)
void dark_channel_kernel(const float* __restrict__ x, float* __restrict__ out) {
    __shared__ float smin[SH][SW2];     // channel-min halo tile (cols col0a .. col0a+79)
    __shared__ float hmin[SH][TILE_W];  // after horizontal 15-min

    const int tid = threadIdx.x;
    const int bx  = blockIdx.x;   // 0..7
    const int by  = blockIdx.y;   // 0..15
    const int b   = blockIdx.z;   // 0..15

    const int base  = b * 3 * CH_STRIDE;
    const int row0  = by * TILE_H - PAD;
    const int col0a = bx * TILE_W - (PAD + 1);  // 16B-aligned halo start

    // ---- stage 1: vectorized load + reflect + channel-min -> smin ----
    // 46 rows x 20 float4-groups = 920 items
    for (int idx = tid; idx < SH * 20; idx += 256) {
        int r  = idx / 20;
        int c4 = idx - r * 20;
        int gr = reflect_idx(row0 + r);
        int gc = col0a + 4 * c4;
        float4 v;
        if (gc >= 0 && gc <= IMG - 4) {
            int off = base + gr * IMG + gc;
            float4 a = *(const float4*)(x + off);
            float4 bb = *(const float4*)(x + off + CH_STRIDE);
            float4 cc = *(const float4*)(x + off + 2 * CH_STRIDE);
            v = fmin4(fmin4(a, bb), cc);
        } else {
            // column-border groups only (bx==0 or bx==7 tiles)
            #pragma unroll
            for (int j = 0; j < 4; ++j) {
                int g   = reflect_idx(gc + j);
                int off = base + gr * IMG + g;
                float m = fminf(fminf(x[off], x[off + CH_STRIDE]), x[off + 2 * CH_STRIDE]);
                if (j == 0) v.x = m; else if (j == 1) v.y = m;
                else if (j == 2) v.z = m; else v.w = m;
            }
        }
        *(float4*)&smin[r][4 * c4] = v;
    }
    __syncthreads();

    // ---- stage 2: horizontal 15-min, 4 outputs per item ----
    // output col c (0..63) needs smin cols c+1 .. c+15 (v-local t+1..t+15)
    // 46 rows x 16 groups = 736 items
    for (int idx = tid; idx < SH * 16; idx += 256) {
        int r  = idx >> 4;
        int c4 = idx & 15;
        const float* rowp = &smin[r][4 * c4];
        float4 v0 = *(const float4*)(rowp);
        float4 v1 = *(const float4*)(rowp + 4);
        float4 v2 = *(const float4*)(rowp + 8);
        float4 v3 = *(const float4*)(rowp + 12);
        float4 v4 = *(const float4*)(rowp + 16);
        // common = min(v[4..15]) = all of v1,v2,v3
        float4 m4 = fmin4(v1, fmin4(v2, v3));
        float common = fminf(fminf(m4.x, m4.y), fminf(m4.z, m4.w));
        float p = fminf(v0.z, v0.w);   // v[2],v[3]
        float s = fminf(v4.x, v4.y);   // v[16],v[17]
        float4 o;
        o.x = fminf(common, fminf(v0.y, p));   // {1,2,3}
        o.y = fminf(common, fminf(p, v4.x));   // {2,3,16}
        o.z = fminf(common, fminf(v0.w, s));   // {3,16,17}
        o.w = fminf(common, fminf(s, v4.z));   // {16,17,18}
        *(float4*)&hmin[r][4 * c4] = o;
    }
    __syncthreads();

    // ---- stage 3: vertical 15-min, 4 output rows per item, coalesced store ----
    // 8 row-groups x 64 cols = 512 items
    for (int idx = tid; idx < (TILE_H / 4) * TILE_W; idx += 256) {
        int rg = idx >> 6;
        int c  = idx & 63;
        int rb = rg * 4;
        float w0  = hmin[rb +  0][c], w1  = hmin[rb +  1][c], w2  = hmin[rb +  2][c];
        float w3  = hmin[rb +  3][c], w4  = hmin[rb +  4][c], w5  = hmin[rb +  5][c];
        float w6  = hmin[rb +  6][c], w7  = hmin[rb +  7][c], w8  = hmin[rb +  8][c];
        float w9  = hmin[rb +  9][c], w10 = hmin[rb + 10][c], w11 = hmin[rb + 11][c];
        float w12 = hmin[rb + 12][c], w13 = hmin[rb + 13][c], w14 = hmin[rb + 14][c];
        float w15 = hmin[rb + 15][c], w16 = hmin[rb + 16][c], w17 = hmin[rb + 17][c];
        // common = min(w3..w14)
        float ca = fminf(fminf(w3, w4),  fminf(w5, w6));
        float cb = fminf(fminf(w7, w8),  fminf(w9, w10));
        float cc = fminf(fminf(w11, w12), fminf(w13, w14));
        float common = fminf(ca, fminf(cb, cc));
        float p = fminf(w1, w2);
        float s = fminf(w15, w16);
        float o0 = fminf(common, fminf(w0, p));    // rows rb+0..rb+14
        float o1 = fminf(common, fminf(p, w15));   // rows rb+1..rb+15
        float o2 = fminf(common, fminf(w2, s));    // rows rb+2..rb+16
        float o3 = fminf(common, fminf(s, w17));   // rows rb+3..rb+17
        int obase = b * CH_STRIDE + (by * TILE_H + rb) * IMG + bx * TILE_W + c;
        out[obase]           = o0;
        out[obase + IMG]     = o1;
        out[obase + 2 * IMG] = o2;
        out[obase + 3 * IMG] = o3;
    }
}

extern "C" void kernel_launch(void* const* d_in, const int* in_sizes, int n_in,
                              void* d_out, int out_size, void* d_ws, size_t ws_size,
                              hipStream_t stream) {
    const float* x = (const float*)d_in[0];
    float* out = (float*)d_out;
    dim3 grid(IMG / TILE_W, IMG / TILE_H, 16);  // 8 x 16 x 16 = 2048 blocks
    dim3 block(256);
    dark_channel_kernel<<<grid, block, 0, stream>>>(x, out);
}

// Round 3
// 27.698 us; speedup vs baseline: 1.1751x; 1.0330x over previous
//
#include <hip/hip_runtime.h>

#define KER    15
#define PAD    7
#define IMG    512
#define TILE_W 64
#define TILE_H 64
#define SH     (TILE_H + 2 * PAD)   // 78
#define SW2    80                   // aligned halo width (need 78, load 80)
#define CH_STRIDE (IMG * IMG)       // 262144
#define NTHREADS 512

__device__ __forceinline__ int reflect_idx(int i) {
    i = i < 0 ? -i : i;
    return i > IMG - 1 ? 2 * (IMG - 1) - i : i;
}

__device__ __forceinline__ float4 fmin4(float4 a, float4 b) {
    float4 r;
    r.x = fminf(a.x, b.x); r.y = fminf(a.y, b.y);
    r.z = fminf(a.z, b.z); r.w = fminf(a.w, b.w);
    return r;
}

__global__ __launch_bounds__(NTHREADS, 8)
void dark_channel_kernel(const float* __restrict__ x, float* __restrict__ out) {
    __shared__ float smin[SH][SW2];   // 78*80*4 = 24960 B; reused in-place for hmin

    const int tid = threadIdx.x;
    const int bx  = blockIdx.x;   // 0..7
    const int by  = blockIdx.y;   // 0..7
    const int b   = blockIdx.z;   // 0..15

    const int base  = b * 3 * CH_STRIDE;
    const int row0  = by * TILE_H - PAD;
    const int col0a = bx * TILE_W - (PAD + 1);  // 16B-aligned halo start

    // ---- stage 1: vectorized load + reflect + channel-min -> smin ----
    // 78 rows x 20 float4-groups = 1560 items; 4 predicated iterations
    #pragma unroll
    for (int it = 0; it < 4; ++it) {
        int idx = tid + it * NTHREADS;
        if (idx < SH * 20) {
            int r  = idx / 20;
            int c4 = idx - r * 20;
            int gr = reflect_idx(row0 + r);
            int gc = col0a + 4 * c4;
            float4 v;
            if (gc >= 0 && gc <= IMG - 4) {
                int off = base + gr * IMG + gc;
                float4 a  = *(const float4*)(x + off);
                float4 bb = *(const float4*)(x + off + CH_STRIDE);
                float4 cc = *(const float4*)(x + off + 2 * CH_STRIDE);
                v = fmin4(fmin4(a, bb), cc);
            } else {
                // column-border groups only (bx==0 or bx==7 tiles)
                #pragma unroll
                for (int j = 0; j < 4; ++j) {
                    int g   = reflect_idx(gc + j);
                    int off = base + gr * IMG + g;
                    float m = fminf(fminf(x[off], x[off + CH_STRIDE]), x[off + 2 * CH_STRIDE]);
                    if (j == 0) v.x = m; else if (j == 1) v.y = m;
                    else if (j == 2) v.z = m; else v.w = m;
                }
            }
            *(float4*)&smin[r][4 * c4] = v;
        }
    }
    __syncthreads();

    // ---- stage 2: horizontal 15-min into registers (static idx), 4 outputs/item ----
    // 78 rows x 16 groups = 1248 items; 3 predicated iterations
    float4 h0, h1, h2;
    #pragma unroll
    for (int it = 0; it < 3; ++it) {
        int idx = tid + it * NTHREADS;
        if (idx < SH * 16) {
            int r  = idx >> 4;
            int c4 = idx & 15;
            const float* rowp = &smin[r][4 * c4];
            float4 v0 = *(const float4*)(rowp);
            float4 v1 = *(const float4*)(rowp + 4);
            float4 v2 = *(const float4*)(rowp + 8);
            float4 v3 = *(const float4*)(rowp + 12);
            float4 v4 = *(const float4*)(rowp + 16);
            float4 m4 = fmin4(v1, fmin4(v2, v3));
            float common = fminf(fminf(m4.x, m4.y), fminf(m4.z, m4.w));
            float p = fminf(v0.z, v0.w);
            float s = fminf(v4.x, v4.y);
            float4 o;
            o.x = fminf(common, fminf(v0.y, p));
            o.y = fminf(common, fminf(p, v4.x));
            o.z = fminf(common, fminf(v0.w, s));
            o.w = fminf(common, fminf(s, v4.z));
            if (it == 0) h0 = o; else if (it == 1) h1 = o; else h2 = o;
        }
    }
    __syncthreads();   // WAR: all reads of smin done before overwrite

    // ---- stage 2b: write hmin back into smin cols 0..63 ----
    #pragma unroll
    for (int it = 0; it < 3; ++it) {
        int idx = tid + it * NTHREADS;
        if (idx < SH * 16) {
            int r  = idx >> 4;
            int c4 = idx & 15;
            float4 o = (it == 0) ? h0 : (it == 1) ? h1 : h2;
            *(float4*)&smin[r][4 * c4] = o;
        }
    }
    __syncthreads();

    // ---- stage 3: vertical 15-min, 4 output rows per item, coalesced store ----
    // 16 row-groups x 64 cols = 1024 items; 2 iterations
    #pragma unroll
    for (int it = 0; it < 2; ++it) {
        int idx = tid + it * NTHREADS;
        int rg = idx >> 6;
        int c  = idx & 63;
        int rb = rg * 4;
        float w0  = smin[rb +  0][c], w1  = smin[rb +  1][c], w2  = smin[rb +  2][c];
        float w3  = smin[rb +  3][c], w4  = smin[rb +  4][c], w5  = smin[rb +  5][c];
        float w6  = smin[rb +  6][c], w7  = smin[rb +  7][c], w8  = smin[rb +  8][c];
        float w9  = smin[rb +  9][c], w10 = smin[rb + 10][c], w11 = smin[rb + 11][c];
        float w12 = smin[rb + 12][c], w13 = smin[rb + 13][c], w14 = smin[rb + 14][c];
        float w15 = smin[rb + 15][c], w16 = smin[rb + 16][c], w17 = smin[rb + 17][c];
        float ca = fminf(fminf(w3, w4),  fminf(w5, w6));
        float cb = fminf(fminf(w7, w8),  fminf(w9, w10));
        float cc = fminf(fminf(w11, w12), fminf(w13, w14));
        float common = fminf(ca, fminf(cb, cc));
        float p = fminf(w1, w2);
        float s = fminf(w15, w16);
        float o0 = fminf(common, fminf(w0, p));
        float o1 = fminf(common, fminf(p, w15));
        float o2 = fminf(common, fminf(w2, s));
        float o3 = fminf(common, fminf(s, w17));
        int obase = b * CH_STRIDE + (by * TILE_H + rb) * IMG + bx * TILE_W + c;
        out[obase]           = o0;
        out[obase + IMG]     = o1;
        out[obase + 2 * IMG] = o2;
        out[obase + 3 * IMG] = o3;
    }
}

extern "C" void kernel_launch(void* const* d_in, const int* in_sizes, int n_in,
                              void* d_out, int out_size, void* d_ws, size_t ws_size,
                              hipStream_t stream) {
    const float* x = (const float*)d_in[0];
    float* out = (float*)d_out;
    dim3 grid(IMG / TILE_W, IMG / TILE_H, 16);  // 8 x 8 x 16 = 1024 blocks
    dim3 block(NTHREADS);
    dark_channel_kernel<<<grid, block, 0, stream>>>(x, out);
}

// Round 4
// 24.688 us; speedup vs baseline: 1.3184x; 1.1219x over previous
//
#include <hip/hip_runtime.h>

#define IMG 512
#define CH_STRIDE (IMG * IMG)   // 262144

__device__ __forceinline__ float4 fmin4(float4 a, float4 b) {
    float4 r;
    r.x = fminf(a.x, b.x); r.y = fminf(a.y, b.y);
    r.z = fminf(a.z, b.z); r.w = fminf(a.w, b.w);
    return r;
}

// ---------------- Kernel 1: channel-min + horizontal 15-min (streaming) ----
// One thread per (img, row, 4-col group). 15 vector loads, ~25 mins, 1 store.
__global__ __launch_bounds__(256)
void hpass(const float* __restrict__ x, float* __restrict__ hmin) {
    int idx = blockIdx.x * 256 + threadIdx.x;   // 16*512*128 = 1,048,576
    int t   = idx & 127;           // 4-col group, out cols 4t..4t+3
    int rr  = idx >> 7;
    int row = rr & 511;
    int img = rr >> 9;

    int bb = 4 * t - 8;
    bb = bb < 0 ? 0 : (bb > IMG - 20 ? IMG - 20 : bb);   // clamped aligned base
    const float* p = x + img * 3 * CH_STRIDE + row * IMG + bb;

    // 15 independent vector loads (deep MLP), then channel-min -> m[0..19] in v0..v4
    float4 a0 = *(const float4*)(p +  0), a1 = *(const float4*)(p +  4),
           a2 = *(const float4*)(p +  8), a3 = *(const float4*)(p + 12),
           a4 = *(const float4*)(p + 16);
    const float* q = p + CH_STRIDE;
    float4 b0 = *(const float4*)(q +  0), b1 = *(const float4*)(q +  4),
           b2 = *(const float4*)(q +  8), b3 = *(const float4*)(q + 12),
           b4 = *(const float4*)(q + 16);
    const float* s2 = p + 2 * CH_STRIDE;
    float4 c0 = *(const float4*)(s2 +  0), c1 = *(const float4*)(s2 +  4),
           c2 = *(const float4*)(s2 +  8), c3 = *(const float4*)(s2 + 12),
           c4 = *(const float4*)(s2 + 16);

    float4 v0 = fmin4(fmin4(a0, b0), c0);
    float4 v1 = fmin4(fmin4(a1, b1), c1);
    float4 v2 = fmin4(fmin4(a2, b2), c2);
    float4 v3 = fmin4(fmin4(a3, b3), c3);
    float4 v4 = fmin4(fmin4(a4, b4), c4);

    // interior: out col 4t+k = min(m[k+1 .. k+15]),  m = v0..v4 flat
    float4 m4 = fmin4(v1, fmin4(v2, v3));
    float common = fminf(fminf(m4.x, m4.y), fminf(m4.z, m4.w));  // min m[4..15]
    float pz = fminf(v0.z, v0.w);   // m2,m3
    float sz = fminf(v4.x, v4.y);   // m16,m17
    float4 o;
    o.x = fminf(common, fminf(v0.y, pz));    // +m1,m2,m3
    o.y = fminf(common, fminf(pz, v4.x));    // +m2,m3,m16
    o.z = fminf(common, fminf(v0.w, sz));    // +m3,m16,m17
    o.w = fminf(common, fminf(sz, v4.z));    // +m16,m17,m18

    if (t < 2) {
        // reflected window at left edge: out col C = min(m[0 .. C+7]) (prefix)
        float pm7  = fminf(fminf(fminf(v0.x, v0.y), fminf(v0.z, v0.w)),
                           fminf(fminf(v1.x, v1.y), fminf(v1.z, v1.w)));  // m0..7
        float pm8  = fminf(pm7,  v2.x);
        float pm9  = fminf(pm8,  v2.y);
        float pm10 = fminf(pm9,  v2.z);
        float pm11 = fminf(pm10, v2.w);
        float pm12 = fminf(pm11, v3.x);
        float pm13 = fminf(pm12, v3.y);
        float pm14 = fminf(pm13, v3.z);
        if (t == 0) { o.x = pm7;  o.y = pm8;  o.z = pm9;  o.w = pm10; }
        else        { o.x = pm11; o.y = pm12; o.z = pm13; o.w = pm14; }
    } else if (t >= 126) {
        // reflected window at right edge: out col C = min(m[C-7-bb .. 19]) (suffix)
        float sm12 = fminf(fminf(fminf(v4.x, v4.y), fminf(v4.z, v4.w)),
                           fminf(fminf(v3.x, v3.y), fminf(v3.z, v3.w)));  // m12..19
        float sm11 = fminf(sm12, v2.w);
        float sm10 = fminf(sm11, v2.z);
        float sm9  = fminf(sm10, v2.y);
        float sm8  = fminf(sm9,  v2.x);
        float sm7  = fminf(sm8,  v1.w);
        float sm6  = fminf(sm7,  v1.z);
        float sm5  = fminf(sm6,  v1.y);
        if (t == 126) { o.x = sm5; o.y = sm6;  o.z = sm7;  o.w = sm8;  }
        else          { o.x = sm9; o.y = sm10; o.z = sm11; o.w = sm12; }
    }

    *(float4*)(hmin + img * CH_STRIDE + row * IMG + 4 * t) = o;
}

// ---------------- Kernel 2: vertical 15-min, van Herk period 16 ------------
// One thread per (img, 16-row segment, 4-col group): 32 loads, ~46 mins, 16 stores.
__global__ __launch_bounds__(256)
void vpass(const float* __restrict__ hmin, float* __restrict__ out) {
    int idx = blockIdx.x * 256 + threadIdx.x;   // 16*32*128 = 65,536
    int c   = idx & 127;
    int ss  = idx >> 7;
    int s   = ss & 31;
    int img = ss >> 5;

    const float* base = hmin + img * CH_STRIDE + 4 * c;
    int r0 = 16 * s - 8;

    float4 A[16], B[16];
    #pragma unroll
    for (int j = 0; j < 16; ++j) {       // rows r0 .. r0+15 (reflect low)
        int r = r0 + j;
        r = r < 0 ? -r : r;
        A[j] = *(const float4*)(base + r * IMG);
    }
    #pragma unroll
    for (int j = 0; j < 16; ++j) {       // rows r0+16 .. r0+31 (reflect high)
        int r = r0 + 16 + j;
        r = r > IMG - 1 ? 2 * (IMG - 1) - r : r;
        B[j] = *(const float4*)(base + r * IMG);
    }

    // in-place suffix min over A: A[j] = min(A[j..15])
    #pragma unroll
    for (int j = 14; j >= 0; --j) A[j] = fmin4(A[j], A[j + 1]);

    float* ob = out + img * CH_STRIDE + (16 * s) * IMG + 4 * c;
    *(float4*)(ob) = A[1];               // k=0: rows r0+1..r0+15, all in A
    float4 pr = B[0];
    #pragma unroll
    for (int k = 1; k <= 14; ++k) {
        *(float4*)(ob + k * IMG) = fmin4(A[k + 1], pr);
        pr = fmin4(pr, B[k]);
    }
    *(float4*)(ob + 15 * IMG) = pr;      // k=15: rows in B only
}

// ---------------- Fallback fused kernel (round-3, known-correct) -----------
#define KER    15
#define PAD    7
#define TILE_W 64
#define TILE_H 64
#define SH     (TILE_H + 2 * PAD)
#define SW2    80
#define NTHREADS 512

__device__ __forceinline__ int reflect_idx(int i) {
    i = i < 0 ? -i : i;
    return i > IMG - 1 ? 2 * (IMG - 1) - i : i;
}

__global__ __launch_bounds__(NTHREADS, 8)
void dark_channel_fused(const float* __restrict__ x, float* __restrict__ out) {
    __shared__ float smin[SH][SW2];
    const int tid = threadIdx.x;
    const int bx  = blockIdx.x;
    const int by  = blockIdx.y;
    const int b   = blockIdx.z;
    const int base  = b * 3 * CH_STRIDE;
    const int row0  = by * TILE_H - PAD;
    const int col0a = bx * TILE_W - (PAD + 1);

    #pragma unroll
    for (int it = 0; it < 4; ++it) {
        int idx = tid + it * NTHREADS;
        if (idx < SH * 20) {
            int r  = idx / 20;
            int c4 = idx - r * 20;
            int gr = reflect_idx(row0 + r);
            int gc = col0a + 4 * c4;
            float4 v;
            if (gc >= 0 && gc <= IMG - 4) {
                int off = base + gr * IMG + gc;
                float4 a  = *(const float4*)(x + off);
                float4 bb = *(const float4*)(x + off + CH_STRIDE);
                float4 cc = *(const float4*)(x + off + 2 * CH_STRIDE);
                v = fmin4(fmin4(a, bb), cc);
            } else {
                #pragma unroll
                for (int j = 0; j < 4; ++j) {
                    int g   = reflect_idx(gc + j);
                    int off = base + gr * IMG + g;
                    float m = fminf(fminf(x[off], x[off + CH_STRIDE]), x[off + 2 * CH_STRIDE]);
                    if (j == 0) v.x = m; else if (j == 1) v.y = m;
                    else if (j == 2) v.z = m; else v.w = m;
                }
            }
            *(float4*)&smin[r][4 * c4] = v;
        }
    }
    __syncthreads();

    float4 h0, h1, h2;
    #pragma unroll
    for (int it = 0; it < 3; ++it) {
        int idx = tid + it * NTHREADS;
        if (idx < SH * 16) {
            int r  = idx >> 4;
            int c4 = idx & 15;
            const float* rowp = &smin[r][4 * c4];
            float4 v0 = *(const float4*)(rowp);
            float4 v1 = *(const float4*)(rowp + 4);
            float4 v2 = *(const float4*)(rowp + 8);
            float4 v3 = *(const float4*)(rowp + 12);
            float4 v4 = *(const float4*)(rowp + 16);
            float4 m4 = fmin4(v1, fmin4(v2, v3));
            float common = fminf(fminf(m4.x, m4.y), fminf(m4.z, m4.w));
            float p = fminf(v0.z, v0.w);
            float s = fminf(v4.x, v4.y);
            float4 o;
            o.x = fminf(common, fminf(v0.y, p));
            o.y = fminf(common, fminf(p, v4.x));
            o.z = fminf(common, fminf(v0.w, s));
            o.w = fminf(common, fminf(s, v4.z));
            if (it == 0) h0 = o; else if (it == 1) h1 = o; else h2 = o;
        }
    }
    __syncthreads();

    #pragma unroll
    for (int it = 0; it < 3; ++it) {
        int idx = tid + it * NTHREADS;
        if (idx < SH * 16) {
            int r  = idx >> 4;
            int c4 = idx & 15;
            float4 o = (it == 0) ? h0 : (it == 1) ? h1 : h2;
            *(float4*)&smin[r][4 * c4] = o;
        }
    }
    __syncthreads();

    #pragma unroll
    for (int it = 0; it < 2; ++it) {
        int idx = tid + it * NTHREADS;
        int rg = idx >> 6;
        int c  = idx & 63;
        int rb = rg * 4;
        float w0  = smin[rb +  0][c], w1  = smin[rb +  1][c], w2  = smin[rb +  2][c];
        float w3  = smin[rb +  3][c], w4  = smin[rb +  4][c], w5  = smin[rb +  5][c];
        float w6  = smin[rb +  6][c], w7  = smin[rb +  7][c], w8  = smin[rb +  8][c];
        float w9  = smin[rb +  9][c], w10 = smin[rb + 10][c], w11 = smin[rb + 11][c];
        float w12 = smin[rb + 12][c], w13 = smin[rb + 13][c], w14 = smin[rb + 14][c];
        float w15 = smin[rb + 15][c], w16 = smin[rb + 16][c], w17 = smin[rb + 17][c];
        float ca = fminf(fminf(w3, w4),  fminf(w5, w6));
        float cb = fminf(fminf(w7, w8),  fminf(w9, w10));
        float cc = fminf(fminf(w11, w12), fminf(w13, w14));
        float common = fminf(ca, fminf(cb, cc));
        float p = fminf(w1, w2);
        float s = fminf(w15, w16);
        int obase = b * CH_STRIDE + (by * TILE_H + rb) * IMG + bx * TILE_W + c;
        out[obase]           = fminf(common, fminf(w0, p));
        out[obase + IMG]     = fminf(common, fminf(p, w15));
        out[obase + 2 * IMG] = fminf(common, fminf(w2, s));
        out[obase + 3 * IMG] = fminf(common, fminf(s, w17));
    }
}

extern "C" void kernel_launch(void* const* d_in, const int* in_sizes, int n_in,
                              void* d_out, int out_size, void* d_ws, size_t ws_size,
                              hipStream_t stream) {
    const float* x = (const float*)d_in[0];
    float* out = (float*)d_out;
    const size_t need = (size_t)16 * CH_STRIDE * sizeof(float);  // 16.8 MB
    if (ws_size >= need && d_ws != nullptr) {
        float* hm = (float*)d_ws;
        hpass<<<dim3(16 * 512 * 128 / 256), dim3(256), 0, stream>>>(x, hm);
        vpass<<<dim3(16 * 32 * 128 / 256),  dim3(256), 0, stream>>>(hm, out);
    } else {
        dim3 grid(IMG / TILE_W, IMG / TILE_H, 16);
        dark_channel_fused<<<grid, dim3(NTHREADS), 0, stream>>>(x, out);
    }
}